// Round 6
// baseline (4363.217 us; speedup 1.0000x reference)
//
#include <hip/hip_runtime.h>
#include <math.h>

// DIORA forward, MI355X. B=32, T=40, D_IN=1024, D=400.
// Per-level compose kernel (L*32 blocks, MLP-restructured) + tiled fp32 GEMM
// (64x128, BK=32) for per-cell transforms. hT (32,820,1200) fp32 in d_ws:
//   inside : [0,400)=h@W_in_top  [400,800)=h@W_in_bot  [800,1200)=h@S_in
//   outside: [0,400)=ho@W_out_top [400,800)=ho@S_out   [800,1200)=h_in@W_out_bot
// obuf (32,820,802): [h_in 400 | s_in 1 | h_out 400 | s_out 1]
// Leaf pre-norm scratch lives in hT[leaf cells][800:1200).

#define TLEN 40
#define DD 400
#define NCELL 820
#define STR 802
#define HT 1200

__host__ __device__ __forceinline__ int coff(int l) { return l * TLEN - (l * (l - 1)) / 2; }

// ---------------- 64x128 / BK=32 fp32 GEMM ----------------
// AMODE 0: A = dense row-major (stride K).  AMODE 1: A = obuf cell rows (+hoff).
// C row mapping: r -> b=r/L, p=r%L, C[((b*NCELL)+cb+p)*HT + co + n].
// B column n selects matrix n/DD from {B0,B1,B2}, col n%DD.
// Bs row padded to 140 floats: ds_write_b128 starting banks (12*r+16*c) mod 32
// are 2-way max (was 8-way at 132).
template<int AMODE>
__global__ __launch_bounds__(256)
void gemm2(const float* __restrict__ A0,
           const float* __restrict__ B0, const float* __restrict__ B1,
           const float* __restrict__ B2,
           const float* __restrict__ bias,
           float* __restrict__ C,
           int M, int N, int K, int L, int cb, int hoff, int co)
{
    __shared__ float As[32][68];
    __shared__ float Bs[32][140];
    const int tid = threadIdx.x;
    const int bm = blockIdx.x, bn = blockIdx.y;

    const int ar = tid & 63;
    const int ak = (tid >> 6) * 8;
    const int rg = bm * 64 + ar;
    const float* Ap = nullptr;
    if (rg < M) {
        if (AMODE == 0) Ap = A0 + (size_t)rg * K;
        else { int b = rg / L, p = rg - b * L;
               Ap = A0 + ((size_t)b * NCELL + cb + p) * STR + hoff; }
    }

    const int bk = tid >> 3;
    const int bc = (tid & 7) * 16;
    const int nb = bn * 128 + bc;
    const float* Bp = nullptr;
    if (nb < N) {
        int mat = nb / DD;
        const float* Bm = (mat == 0) ? B0 : ((mat == 1) ? B1 : B2);
        Bp = Bm + (nb - mat * DD);
    }

    float acc[4][8];
    #pragma unroll
    for (int i = 0; i < 4; ++i)
        #pragma unroll
        for (int j = 0; j < 8; ++j) acc[i][j] = 0.f;

    const int ty = tid >> 4;
    const int tx = tid & 15;

    for (int k0 = 0; k0 < K; k0 += 32) {
        float av[8];
        if (Ap && (k0 + ak) < K) {
            if (AMODE == 0) {
                float4 p0 = *(const float4*)(Ap + k0 + ak);
                float4 p1 = *(const float4*)(Ap + k0 + ak + 4);
                av[0] = p0.x; av[1] = p0.y; av[2] = p0.z; av[3] = p0.w;
                av[4] = p1.x; av[5] = p1.y; av[6] = p1.z; av[7] = p1.w;
            } else {
                #pragma unroll
                for (int i = 0; i < 8; ++i) av[i] = Ap[k0 + ak + i];
            }
        } else {
            #pragma unroll
            for (int i = 0; i < 8; ++i) av[i] = 0.f;
        }
        float4 bv[4];
        if (Bp && (k0 + bk) < K) {
            const float* bp = Bp + (size_t)(k0 + bk) * DD;
            bv[0] = *(const float4*)(bp);
            bv[1] = *(const float4*)(bp + 4);
            bv[2] = *(const float4*)(bp + 8);
            bv[3] = *(const float4*)(bp + 12);
        } else {
            bv[0] = bv[1] = bv[2] = bv[3] = make_float4(0.f, 0.f, 0.f, 0.f);
        }
        __syncthreads();
        #pragma unroll
        for (int i = 0; i < 8; ++i) As[ak + i][ar] = av[i];
        *(float4*)&Bs[bk][bc + 0]  = bv[0];
        *(float4*)&Bs[bk][bc + 4]  = bv[1];
        *(float4*)&Bs[bk][bc + 8]  = bv[2];
        *(float4*)&Bs[bk][bc + 12] = bv[3];
        __syncthreads();

        #pragma unroll
        for (int k = 0; k < 32; ++k) {
            float4 a  = *(const float4*)&As[k][ty * 4];
            float4 b0 = *(const float4*)&Bs[k][tx * 4];
            float4 b1 = *(const float4*)&Bs[k][64 + tx * 4];
            float ai[4] = {a.x, a.y, a.z, a.w};
            float bj[8] = {b0.x, b0.y, b0.z, b0.w, b1.x, b1.y, b1.z, b1.w};
            #pragma unroll
            for (int i = 0; i < 4; ++i)
                #pragma unroll
                for (int j = 0; j < 8; ++j) acc[i][j] += ai[i] * bj[j];
        }
    }

    #pragma unroll
    for (int i = 0; i < 4; ++i) {
        int r = bm * 64 + ty * 4 + i;
        if (r >= M) continue;
        int b = r / L, p = r - b * L;
        size_t crow = ((size_t)b * NCELL + cb + p) * HT + co;
        #pragma unroll
        for (int j = 0; j < 8; ++j) {
            int n = bn * 128 + ((j < 4) ? (tx * 4 + j) : (64 + tx * 4 + j - 4));
            if (n >= N) continue;
            float v = acc[i][j];
            if (bias) v = fmaxf(v + bias[n], 0.f);
            C[crow + n] = v;
        }
    }
}

// ---------------- normalize leaf rows (pre-norm scratch in hT [800:1200)) ----
__global__ __launch_bounds__(256)
void unit_leaf(float* obuf, const float* __restrict__ hT)
{
    int w = threadIdx.x >> 6, lane = threadIdx.x & 63;
    int r = blockIdx.x * 4 + w;                 // 0..1279 = (b, pos)
    int b = r / TLEN, pos = r - b * TLEN;
    const float* t = hT + ((size_t)b * NCELL + pos) * HT + 800;
    float ss = 0.f;
    for (int f = lane; f < DD; f += 64) { float v = t[f]; ss += v * v; }
    #pragma unroll
    for (int o = 32; o; o >>= 1) ss += __shfl_xor(ss, o);
    float rinv = 1.f / (sqrtf(ss) + 1e-8f);
    size_t orow = ((size_t)b * NCELL + pos) * STR;
    for (int f = lane; f < DD; f += 64) obuf[orow + f] = t[f] * rinv;
    if (lane == 0) obuf[orow + DD] = 0.f;       // s_in(leaf)=0
}

// ---------------- per-level compose (MLP-restructured) ----------------
// Phase A: scores (8-lane-group float2 dots).  Softmax on wave 0.
// Phase B: relu(hA+hB+bias) as a flat job pool into a 16-k LDS chunk
//          (all loads independent -> deep memory queue), then p-weighted
//          accumulation from LDS into registers. Chunked to cap LDS at 28KB.
template<int INSIDE>
__global__ __launch_bounds__(256)
void compose_kernel(int lv, float* obuf, const float* __restrict__ hT,
                    const float* __restrict__ bias)
{
    const int nk  = INSIDE ? lv : (TLEN - 1 - lv);
    const int b   = blockIdx.x & 31;
    const int pos = blockIdx.x >> 5;
    const int cell = coff(lv) + pos;
    const int tid = threadIdx.x;
    const int bco = INSIDE ? 400 : 800;   // hB column offset in hT
    const int sco = INSIDE ? 800 : 400;   // score-vector column offset in hT
    const int sA  = INSIDE ? DD : (STR - 1);  // s-term offset for i1 in obuf

    __shared__ int   o1s[TLEN], o2s[TLEN], q1s[TLEN], q2s[TLEN];
    __shared__ float sbs[TLEN], ps[TLEN];
    __shared__ float bsh[DD];
    __shared__ float rbuf[16][DD];
    __shared__ float red[4];
    __shared__ float sh_snew;

    if (tid < nk) {
        int k = tid, i1, i2;
        if (INSIDE) {
            i1 = coff(k) + pos;
            i2 = coff(lv - k - 1) + pos + k + 1;
        } else {
            if (k < pos) { i1 = coff(lv + k + 1) + pos - k - 1; i2 = coff(k) + pos - k - 1; }
            else         { int j = k - pos; i1 = coff(lv + j + 1) + pos; i2 = coff(j) + pos + lv + 1; }
        }
        o1s[k] = (b * NCELL + i1) * HT;
        o2s[k] = (b * NCELL + i2) * HT;
        q1s[k] = (b * NCELL + i1) * STR;
        q2s[k] = (b * NCELL + i2) * STR;
    }
    for (int f = tid; f < DD; f += 256) bsh[f] = bias[f];
    __syncthreads();

    // Phase A: scores sb_k = dot(hS[i1], h_in[i2]) + s1 + s2
    {
        const int g = tid >> 3, gl = tid & 7;
        for (int k = g; k < nk; k += 32) {
            const float2* v1 = (const float2*)(hT + o1s[k] + sco);
            const float2* v2 = (const float2*)(obuf + q2s[k]);
            float ax = 0.f, ay = 0.f;
            #pragma unroll 5
            for (int j = gl; j < 200; j += 8) {
                float2 a = v1[j], c = v2[j];
                ax += a.x * c.x; ay += a.y * c.y;
            }
            float acc = ax + ay;
            acc += __shfl_xor(acc, 4);
            acc += __shfl_xor(acc, 2);
            acc += __shfl_xor(acc, 1);
            if (gl == 0)
                sbs[k] = acc + obuf[q1s[k] + sA] + obuf[q2s[k] + DD];
        }
    }
    __syncthreads();

    // softmax (wave 0), also s_new = sum p*sb
    if (tid < 64) {
        float v = (tid < nk) ? sbs[tid] : -INFINITY;
        float m = v;
        #pragma unroll
        for (int o = 32; o; o >>= 1) m = fmaxf(m, __shfl_xor(m, o));
        float e = (tid < nk) ? __expf(v - m) : 0.f;
        float s = e;
        #pragma unroll
        for (int o = 32; o; o >>= 1) s += __shfl_xor(s, o);
        float p = e / s;
        if (tid < nk) ps[tid] = p;
        float pv = (tid < nk) ? p * v : 0.f;
        #pragma unroll
        for (int o = 32; o; o >>= 1) pv += __shfl_xor(pv, o);
        if (tid == 0) sh_snew = pv;
    }
    __syncthreads();

    // Phase B: chunked relu-term pool + weighted accumulation
    float2 hacc = make_float2(0.f, 0.f);     // valid for tid < 200
    for (int c0 = 0; c0 < nk; c0 += 16) {
        const int kn = (nk - c0 < 16) ? (nk - c0) : 16;
        const int nj = kn * 200;
        for (int idx = tid; idx < nj; idx += 256) {
            int k = idx / 200, f2 = idx - k * 200;
            int f = 2 * f2;
            float2 a = *(const float2*)(hT + o1s[c0 + k] + f);
            float2 c = *(const float2*)(hT + o2s[c0 + k] + bco + f);
            float2 r;
            r.x = fmaxf(a.x + c.x + bsh[f], 0.f);
            r.y = fmaxf(a.y + c.y + bsh[f + 1], 0.f);
            *(float2*)&rbuf[k][f] = r;
        }
        __syncthreads();
        if (tid < 200) {
            #pragma unroll 4
            for (int k = 0; k < kn; ++k) {
                float2 r = *(const float2*)&rbuf[k][2 * tid];
                float p = ps[c0 + k];
                hacc.x += p * r.x; hacc.y += p * r.y;
            }
        }
        __syncthreads();
    }

    // stash h_new into rbuf[0], then normalize
    if (tid < 200) *(float2*)&rbuf[0][2 * tid] = hacc;
    __syncthreads();

    float ss = 0.f;
    for (int f = tid; f < DD; f += 256) { float v = rbuf[0][f]; ss += v * v; }
    #pragma unroll
    for (int o = 32; o; o >>= 1) ss += __shfl_xor(ss, o);
    if ((tid & 63) == 0) red[tid >> 6] = ss;
    __syncthreads();
    float rinv = 1.f / (sqrtf(red[0] + red[1] + red[2] + red[3]) + 1e-8f);

    const int hoff = INSIDE ? 0 : (DD + 1);
    const int soff = INSIDE ? DD : (STR - 1);
    size_t orow = ((size_t)(b * NCELL) + cell) * STR;
    for (int f = tid; f < DD; f += 256) obuf[orow + hoff + f] = rbuf[0][f] * rinv;
    if (tid == 0) obuf[orow + soff] = sh_snew;
}

// ---------------- root transforms: hT[root][0:800) = [u@Wout_top | u@Sout] ----
__global__ __launch_bounds__(256)
void root_trans(const float* __restrict__ rooth, const float* __restrict__ Wout,
                const float* __restrict__ Sout, float* __restrict__ hT)
{
    const int tid = threadIdx.x;
    __shared__ float u[DD];
    __shared__ float red[4];
    __shared__ float part[4][64];
    float ss = 0.f;
    for (int f = tid; f < DD; f += 256) { float v = rooth[f]; ss += v * v; }
    #pragma unroll
    for (int o = 32; o; o >>= 1) ss += __shfl_xor(ss, o);
    if ((tid & 63) == 0) red[tid >> 6] = ss;
    __syncthreads();
    float rinv = 1.f / (sqrtf(red[0] + red[1] + red[2] + red[3]) + 1e-8f);
    for (int f = tid; f < DD; f += 256) u[f] = rooth[f] * rinv;
    __syncthreads();

    const int w = tid >> 6, lane = tid & 63;
    const int n = blockIdx.x * 64 + lane;
    float acc = 0.f;
    if (n < 800) {
        int mat = n / DD;
        const float* Mp = mat ? Sout : Wout;
        int c = n - mat * DD;
        #pragma unroll 4
        for (int k = w * 100; k < w * 100 + 100; ++k) acc += u[k] * Mp[(size_t)k * DD + c];
    }
    part[w][lane] = acc;
    __syncthreads();
    if (w == 0 && n < 800) {
        float v = part[0][lane] + part[1][lane] + part[2][lane] + part[3][lane];
        for (int b = 0; b < 32; ++b)
            hT[((size_t)b * NCELL + NCELL - 1) * HT + n] = v;
    }
}

// ---------------- root h_out/s_out into obuf ----------------
__global__ __launch_bounds__(256)
void root_write(const float* __restrict__ rooth, float* obuf)
{
    const int b = blockIdx.x;
    const int tid = threadIdx.x;
    __shared__ float red[4];
    float ss = 0.f;
    for (int f = tid; f < DD; f += 256) { float v = rooth[f]; ss += v * v; }
    #pragma unroll
    for (int o = 32; o; o >>= 1) ss += __shfl_xor(ss, o);
    if ((tid & 63) == 0) red[tid >> 6] = ss;
    __syncthreads();
    float rinv = 1.f / (sqrtf(red[0] + red[1] + red[2] + red[3]) + 1e-8f);
    size_t orow = ((size_t)b * NCELL + NCELL - 1) * STR;
    for (int f = tid; f < DD; f += 256) obuf[orow + DD + 1 + f] = rooth[f] * rinv;
    if (tid == 0) obuf[orow + STR - 1] = 0.f;
}

extern "C" void kernel_launch(void* const* d_in, const int* in_sizes, int n_in,
                              void* d_out, int out_size, void* d_ws, size_t ws_size,
                              hipStream_t stream)
{
    const float* x     = (const float*)d_in[0];
    const float* Wl    = (const float*)d_in[1];
    const float* blf   = (const float*)d_in[2];
    const float* Win   = (const float*)d_in[3];
    const float* bin   = (const float*)d_in[4];
    const float* Sin   = (const float*)d_in[5];
    const float* Wout  = (const float*)d_in[6];
    const float* bout  = (const float*)d_in[7];
    const float* Sout  = (const float*)d_in[8];
    const float* rooth = (const float*)d_in[9];

    float* obuf = (float*)d_out;
    float* hT   = (float*)d_ws;     // 32*820*1200 fp32 = ~126 MB

    // leaf projection: relu(x @ W_leaf + b) -> hT[leaf cells][800:1200)
    {
        dim3 g(20, 4);              // M=1280/64, N=400/128
        gemm2<0><<<g, 256, 0, stream>>>(x, Wl, nullptr, nullptr, blf, hT,
                                        1280, 400, 1024, TLEN, 0, 0, 800);
    }
    unit_leaf<<<320, 256, 0, stream>>>(obuf, hT);

    // inside pass
    for (int lv = 0; lv < TLEN; ++lv) {
        int L = TLEN - lv;
        int cb = coff(lv);
        if (lv > 0)
            compose_kernel<1><<<L * 32, 256, 0, stream>>>(lv, obuf, hT, bin);
        if (lv < TLEN - 1) {
            int M = L * 32;
            dim3 g((M + 63) / 64, 10);
            gemm2<1><<<g, 256, 0, stream>>>(obuf, Win, Win + DD * DD, Sin,
                                            nullptr, hT, M, 1200, DD, L, cb, 0, 0);
        }
    }

    // prep: hT[:,:,800:1200) = h_in @ W_out_bot for ALL cells
    {
        dim3 g(410, 4);             // M=26240/64, N=400/128
        gemm2<1><<<g, 256, 0, stream>>>(obuf, Wout + DD * DD, nullptr, nullptr,
                                        nullptr, hT, 32 * NCELL, 400, DD, NCELL, 0, 0, 800);
    }
    root_trans<<<13, 256, 0, stream>>>(rooth, Wout, Sout, hT);
    root_write<<<32, 256, 0, stream>>>(rooth, obuf);

    // outside pass
    for (int lv = TLEN - 2; lv >= 0; --lv) {
        int L = TLEN - lv;
        int cb = coff(lv);
        compose_kernel<0><<<L * 32, 256, 0, stream>>>(lv, obuf, hT, bout);
        if (lv > 0) {
            int M = L * 32;
            dim3 g((M + 63) / 64, 7);
            gemm2<1><<<g, 256, 0, stream>>>(obuf, Wout, Sout, nullptr,
                                            nullptr, hT, M, 800, DD, L, cb, DD + 1, 0);
        }
    }
}

// Round 7
// 4171.530 us; speedup vs baseline: 1.0460x; 1.0460x over previous
//
#include <hip/hip_runtime.h>
#include <hip/hip_bf16.h>
#include <math.h>

// DIORA forward, MI355X. B=32, T=40, D_IN=1024, D=400.
// Transform state split for L3 residency (189MB total vs 256MB L3):
//   hAB (32,820,800) bf16 in ws: [0,400)=hA, [400,800)=hB
//     inside : hA=h@W_in_top, hB=h@W_in_bot
//     outside: hA=ho@W_out_top, hB=h_in@W_out_bot (prep, done once)
//   hC (32,820,400) fp32 in ws: inside h@S_in, outside ho@S_out  (score path
//     stays fp32 end-to-end; bf16 only on the relu-MLP path, damped by unit()).
// obuf (32,820,802) fp32 = d_out: [h_in 400 | s_in 1 | h_out 400 | s_out 1]
// Leaf pre-norm relu scratch lives in hC[leaf cells] (consumed by unit_leaf
// before the lv-0 inside GEMM overwrites it).

#define TLEN 40
#define DD 400
#define NCELL 820
#define STR 802

__host__ __device__ __forceinline__ int coff(int l) { return l * TLEN - (l * (l - 1)) / 2; }
__device__ __forceinline__ float bf2f(unsigned short u) {
    return __uint_as_float(((unsigned)u) << 16);
}
__device__ __forceinline__ unsigned short f2bf(float v) {
    __hip_bfloat16 h = __float2bfloat16(v);
    return *reinterpret_cast<unsigned short*>(&h);
}

// ---------------- 64x128 / BK=32 fp32 GEMM, split bf16/fp32 output ----------
// AMODE 0: A = dense row-major (stride K).  AMODE 1: A = obuf cell rows (+hoff).
// Output row r -> b=r/L, p=r%L, cell=cb+p.
//   col n < nsplit : Cb[cell_row*800 + co_b + n]          (bf16)
//   col n >= nsplit: Cf[cell_row*400 + (n - nsplit)]      (fp32)
// B column n selects matrix n/DD from {B0,B1,B2}, col n%DD.
template<int AMODE>
__global__ __launch_bounds__(256)
void gemm2(const float* __restrict__ A0,
           const float* __restrict__ B0, const float* __restrict__ B1,
           const float* __restrict__ B2,
           const float* __restrict__ bias,
           unsigned short* __restrict__ Cb, float* __restrict__ Cf,
           int M, int N, int K, int L, int cb, int hoff, int co_b, int nsplit)
{
    __shared__ float As[32][68];
    __shared__ float Bs[32][140];
    const int tid = threadIdx.x;
    const int bm = blockIdx.x, bn = blockIdx.y;

    const int ar = tid & 63;
    const int ak = (tid >> 6) * 8;
    const int rg = bm * 64 + ar;
    const float* Ap = nullptr;
    if (rg < M) {
        if (AMODE == 0) Ap = A0 + (size_t)rg * K;
        else { int b = rg / L, p = rg - b * L;
               Ap = A0 + ((size_t)b * NCELL + cb + p) * STR + hoff; }
    }

    const int bk = tid >> 3;
    const int bc = (tid & 7) * 16;
    const int nb = bn * 128 + bc;
    const float* Bp = nullptr;
    if (nb < N) {
        int mat = nb / DD;
        const float* Bm = (mat == 0) ? B0 : ((mat == 1) ? B1 : B2);
        Bp = Bm + (nb - mat * DD);
    }

    float acc[4][8];
    #pragma unroll
    for (int i = 0; i < 4; ++i)
        #pragma unroll
        for (int j = 0; j < 8; ++j) acc[i][j] = 0.f;

    const int ty = tid >> 4;
    const int tx = tid & 15;

    for (int k0 = 0; k0 < K; k0 += 32) {
        float av[8];
        if (Ap && (k0 + ak) < K) {
            if (AMODE == 0) {
                float4 p0 = *(const float4*)(Ap + k0 + ak);
                float4 p1 = *(const float4*)(Ap + k0 + ak + 4);
                av[0] = p0.x; av[1] = p0.y; av[2] = p0.z; av[3] = p0.w;
                av[4] = p1.x; av[5] = p1.y; av[6] = p1.z; av[7] = p1.w;
            } else {
                #pragma unroll
                for (int i = 0; i < 8; ++i) av[i] = Ap[k0 + ak + i];
            }
        } else {
            #pragma unroll
            for (int i = 0; i < 8; ++i) av[i] = 0.f;
        }
        float4 bv[4];
        if (Bp && (k0 + bk) < K) {
            const float* bp = Bp + (size_t)(k0 + bk) * DD;
            bv[0] = *(const float4*)(bp);
            bv[1] = *(const float4*)(bp + 4);
            bv[2] = *(const float4*)(bp + 8);
            bv[3] = *(const float4*)(bp + 12);
        } else {
            bv[0] = bv[1] = bv[2] = bv[3] = make_float4(0.f, 0.f, 0.f, 0.f);
        }
        __syncthreads();
        #pragma unroll
        for (int i = 0; i < 8; ++i) As[ak + i][ar] = av[i];
        *(float4*)&Bs[bk][bc + 0]  = bv[0];
        *(float4*)&Bs[bk][bc + 4]  = bv[1];
        *(float4*)&Bs[bk][bc + 8]  = bv[2];
        *(float4*)&Bs[bk][bc + 12] = bv[3];
        __syncthreads();

        #pragma unroll
        for (int k = 0; k < 32; ++k) {
            float4 a  = *(const float4*)&As[k][ty * 4];
            float4 b0 = *(const float4*)&Bs[k][tx * 4];
            float4 b1 = *(const float4*)&Bs[k][64 + tx * 4];
            float ai[4] = {a.x, a.y, a.z, a.w};
            float bj[8] = {b0.x, b0.y, b0.z, b0.w, b1.x, b1.y, b1.z, b1.w};
            #pragma unroll
            for (int i = 0; i < 4; ++i)
                #pragma unroll
                for (int j = 0; j < 8; ++j) acc[i][j] += ai[i] * bj[j];
        }
    }

    #pragma unroll
    for (int i = 0; i < 4; ++i) {
        int r = bm * 64 + ty * 4 + i;
        if (r >= M) continue;
        int b = r / L, p = r - b * L;
        size_t cell = (size_t)b * NCELL + cb + p;
        size_t rb = cell * 800 + co_b;
        size_t rf = cell * 400;
        #pragma unroll
        for (int j = 0; j < 8; ++j) {
            int n = bn * 128 + ((j < 4) ? (tx * 4 + j) : (64 + tx * 4 + j - 4));
            if (n >= N) continue;
            float v = acc[i][j];
            if (bias) v = fmaxf(v + bias[n], 0.f);
            if (n < nsplit) Cb[rb + n] = f2bf(v);
            else            Cf[rf + n - nsplit] = v;
        }
    }
}

// ---------------- normalize leaf rows (pre-norm scratch in hC) ----------
__global__ __launch_bounds__(256)
void unit_leaf(float* obuf, const float* __restrict__ hC)
{
    int w = threadIdx.x >> 6, lane = threadIdx.x & 63;
    int r = blockIdx.x * 4 + w;                 // 0..1279 = (b, pos)
    int b = r / TLEN, pos = r - b * TLEN;
    const float* t = hC + ((size_t)b * NCELL + pos) * 400;
    float ss = 0.f;
    for (int f = lane; f < DD; f += 64) { float v = t[f]; ss += v * v; }
    #pragma unroll
    for (int o = 32; o; o >>= 1) ss += __shfl_xor(ss, o);
    float rinv = 1.f / (sqrtf(ss) + 1e-8f);
    size_t orow = ((size_t)b * NCELL + pos) * STR;
    for (int f = lane; f < DD; f += 64) obuf[orow + f] = t[f] * rinv;
    if (lane == 0) obuf[orow + DD] = 0.f;       // s_in(leaf)=0
}

// ---------------- per-level compose ----------------
// Score path fp32 (hC + obuf). MLP path bf16 (hAB), register accumulation.
template<int INSIDE>
__global__ __launch_bounds__(256)
void compose_kernel(int lv, float* obuf, const unsigned short* __restrict__ hAB,
                    const float* __restrict__ hC, const float* __restrict__ bias)
{
    const int nk  = INSIDE ? lv : (TLEN - 1 - lv);
    const int b   = blockIdx.x & 31;
    const int pos = blockIdx.x >> 5;
    const int cell = coff(lv) + pos;
    const int tid = threadIdx.x;
    const int sA  = INSIDE ? DD : (STR - 1);  // s-term offset for i1 in obuf

    __shared__ int   o1s[TLEN], o2s[TLEN], c1s[TLEN], q1s[TLEN], q2s[TLEN];
    __shared__ float sbs[TLEN], ps[TLEN];
    __shared__ float bsh[DD];
    __shared__ float hnew[DD];
    __shared__ float red[4];
    __shared__ float sh_snew;

    if (tid < nk) {
        int k = tid, i1, i2;
        if (INSIDE) {
            i1 = coff(k) + pos;
            i2 = coff(lv - k - 1) + pos + k + 1;
        } else {
            if (k < pos) { i1 = coff(lv + k + 1) + pos - k - 1; i2 = coff(k) + pos - k - 1; }
            else         { int j = k - pos; i1 = coff(lv + j + 1) + pos; i2 = coff(j) + pos + lv + 1; }
        }
        o1s[k] = (b * NCELL + i1) * 800;        // hA (bf16)
        o2s[k] = (b * NCELL + i2) * 800 + 400;  // hB (bf16)
        c1s[k] = (b * NCELL + i1) * 400;        // hC (fp32, scores)
        q1s[k] = (b * NCELL + i1) * STR;
        q2s[k] = (b * NCELL + i2) * STR;
    }
    for (int f = tid; f < DD; f += 256) bsh[f] = bias[f];
    __syncthreads();

    // Phase A: scores sb_k = dot(hC[i1], h_in[i2]) + s1 + s2   (fp32)
    {
        const int g = tid >> 3, gl = tid & 7;
        for (int k = g; k < nk; k += 32) {
            const float2* v1 = (const float2*)(hC + c1s[k]);
            const float2* v2 = (const float2*)(obuf + q2s[k]);
            float ax = 0.f, ay = 0.f;
            #pragma unroll 5
            for (int j = gl; j < 200; j += 8) {
                float2 a = v1[j], c = v2[j];
                ax += a.x * c.x; ay += a.y * c.y;
            }
            float acc = ax + ay;
            acc += __shfl_xor(acc, 4);
            acc += __shfl_xor(acc, 2);
            acc += __shfl_xor(acc, 1);
            if (gl == 0)
                sbs[k] = acc + obuf[q1s[k] + sA] + obuf[q2s[k] + DD];
        }
    }
    __syncthreads();

    // softmax (wave 0), also s_new = sum p*sb
    if (tid < 64) {
        float v = (tid < nk) ? sbs[tid] : -INFINITY;
        float m = v;
        #pragma unroll
        for (int o = 32; o; o >>= 1) m = fmaxf(m, __shfl_xor(m, o));
        float e = (tid < nk) ? __expf(v - m) : 0.f;
        float s = e;
        #pragma unroll
        for (int o = 32; o; o >>= 1) s += __shfl_xor(s, o);
        float p = e / s;
        if (tid < nk) ps[tid] = p;
        float pv = (tid < nk) ? p * v : 0.f;
        #pragma unroll
        for (int o = 32; o; o >>= 1) pv += __shfl_xor(pv, o);
        if (tid == 0) sh_snew = pv;
    }
    __syncthreads();

    // Phase B: h_new = sum_k p_k * relu(hA[i1] + hB[i2] + bias)   (bf16 loads)
    if (tid < 200) {
        const int f = 2 * tid;
        const float bf0 = bsh[f], bf1 = bsh[f + 1];
        float ax = 0.f, ay = 0.f;
        #pragma unroll 4
        for (int k = 0; k < nk; ++k) {
            ushort2 a = *(const ushort2*)(hAB + o1s[k] + f);
            ushort2 c = *(const ushort2*)(hAB + o2s[k] + f);
            float p = ps[k];
            ax += p * fmaxf(bf2f(a.x) + bf2f(c.x) + bf0, 0.f);
            ay += p * fmaxf(bf2f(a.y) + bf2f(c.y) + bf1, 0.f);
        }
        hnew[f] = ax; hnew[f + 1] = ay;
    }
    __syncthreads();

    // norm
    float ss = 0.f;
    for (int f = tid; f < DD; f += 256) { float v = hnew[f]; ss += v * v; }
    #pragma unroll
    for (int o = 32; o; o >>= 1) ss += __shfl_xor(ss, o);
    if ((tid & 63) == 0) red[tid >> 6] = ss;
    __syncthreads();
    float rinv = 1.f / (sqrtf(red[0] + red[1] + red[2] + red[3]) + 1e-8f);

    const int hoff = INSIDE ? 0 : (DD + 1);
    const int soff = INSIDE ? DD : (STR - 1);
    size_t orow = ((size_t)(b * NCELL) + cell) * STR;
    for (int f = tid; f < DD; f += 256) obuf[orow + hoff + f] = hnew[f] * rinv;
    if (tid == 0) obuf[orow + soff] = sh_snew;
}

// ---------------- root transforms: hA[root]=u@Wout_top (bf16), hC[root]=u@Sout
__global__ __launch_bounds__(256)
void root_trans(const float* __restrict__ rooth, const float* __restrict__ Wout,
                const float* __restrict__ Sout,
                unsigned short* __restrict__ hAB, float* __restrict__ hC)
{
    const int tid = threadIdx.x;
    __shared__ float u[DD];
    __shared__ float red[4];
    __shared__ float part[4][64];
    float ss = 0.f;
    for (int f = tid; f < DD; f += 256) { float v = rooth[f]; ss += v * v; }
    #pragma unroll
    for (int o = 32; o; o >>= 1) ss += __shfl_xor(ss, o);
    if ((tid & 63) == 0) red[tid >> 6] = ss;
    __syncthreads();
    float rinv = 1.f / (sqrtf(red[0] + red[1] + red[2] + red[3]) + 1e-8f);
    for (int f = tid; f < DD; f += 256) u[f] = rooth[f] * rinv;
    __syncthreads();

    const int w = tid >> 6, lane = tid & 63;
    const int n = blockIdx.x * 64 + lane;
    float acc = 0.f;
    if (n < 800) {
        int mat = n / DD;
        const float* Mp = mat ? Sout : Wout;
        int c = n - mat * DD;
        #pragma unroll 4
        for (int k = w * 100; k < w * 100 + 100; ++k) acc += u[k] * Mp[(size_t)k * DD + c];
    }
    part[w][lane] = acc;
    __syncthreads();
    if (w == 0 && n < 800) {
        float v = part[0][lane] + part[1][lane] + part[2][lane] + part[3][lane];
        if (n < 400) {
            unsigned short bv = f2bf(v);
            for (int b = 0; b < 32; ++b)
                hAB[((size_t)b * NCELL + NCELL - 1) * 800 + n] = bv;
        } else {
            for (int b = 0; b < 32; ++b)
                hC[((size_t)b * NCELL + NCELL - 1) * 400 + (n - 400)] = v;
        }
    }
}

// ---------------- root h_out/s_out into obuf ----------------
__global__ __launch_bounds__(256)
void root_write(const float* __restrict__ rooth, float* obuf)
{
    const int b = blockIdx.x;
    const int tid = threadIdx.x;
    __shared__ float red[4];
    float ss = 0.f;
    for (int f = tid; f < DD; f += 256) { float v = rooth[f]; ss += v * v; }
    #pragma unroll
    for (int o = 32; o; o >>= 1) ss += __shfl_xor(ss, o);
    if ((tid & 63) == 0) red[tid >> 6] = ss;
    __syncthreads();
    float rinv = 1.f / (sqrtf(red[0] + red[1] + red[2] + red[3]) + 1e-8f);
    size_t orow = ((size_t)b * NCELL + NCELL - 1) * STR;
    for (int f = tid; f < DD; f += 256) obuf[orow + DD + 1 + f] = rooth[f] * rinv;
    if (tid == 0) obuf[orow + STR - 1] = 0.f;
}

extern "C" void kernel_launch(void* const* d_in, const int* in_sizes, int n_in,
                              void* d_out, int out_size, void* d_ws, size_t ws_size,
                              hipStream_t stream)
{
    const float* x     = (const float*)d_in[0];
    const float* Wl    = (const float*)d_in[1];
    const float* blf   = (const float*)d_in[2];
    const float* Win   = (const float*)d_in[3];
    const float* bin   = (const float*)d_in[4];
    const float* Sin   = (const float*)d_in[5];
    const float* Wout  = (const float*)d_in[6];
    const float* bout  = (const float*)d_in[7];
    const float* Sout  = (const float*)d_in[8];
    const float* rooth = (const float*)d_in[9];

    float* obuf = (float*)d_out;
    unsigned short* hAB = (unsigned short*)d_ws;                 // 42 MB bf16
    float* hC = (float*)((char*)d_ws + (size_t)32 * NCELL * 800 * 2);  // 42 MB fp32

    // leaf projection: relu(x @ W_leaf + b) -> hC[leaf cells] (fp32 scratch)
    {
        dim3 g(20, 4);              // M=1280/64, N=400/128
        gemm2<0><<<g, 256, 0, stream>>>(x, Wl, nullptr, nullptr, blf, hAB, hC,
                                        1280, 400, 1024, TLEN, 0, 0, 0, 0);
    }
    unit_leaf<<<320, 256, 0, stream>>>(obuf, hC);

    // inside pass
    for (int lv = 0; lv < TLEN; ++lv) {
        int L = TLEN - lv;
        int cb = coff(lv);
        if (lv > 0)
            compose_kernel<1><<<L * 32, 256, 0, stream>>>(lv, obuf, hAB, hC, bin);
        if (lv < TLEN - 1) {
            int M = L * 32;
            dim3 g((M + 63) / 64, 10);   // N=1200
            gemm2<1><<<g, 256, 0, stream>>>(obuf, Win, Win + DD * DD, Sin,
                                            nullptr, hAB, hC, M, 1200, DD, L, cb, 0, 0, 800);
        }
    }

    // prep: hAB[:, 400:800) = h_in @ W_out_bot for ALL cells (bf16)
    {
        dim3 g(410, 4);             // M=26240/64, N=400/128
        gemm2<1><<<g, 256, 0, stream>>>(obuf, Wout + DD * DD, nullptr, nullptr,
                                        nullptr, hAB, hC, 32 * NCELL, 400, DD, NCELL,
                                        0, 0, 400, 400);
    }
    root_trans<<<13, 256, 0, stream>>>(rooth, Wout, Sout, hAB, hC);
    root_write<<<32, 256, 0, stream>>>(rooth, obuf);

    // outside pass
    for (int lv = TLEN - 2; lv >= 0; --lv) {
        int L = TLEN - lv;
        int cb = coff(lv);
        compose_kernel<0><<<L * 32, 256, 0, stream>>>(lv, obuf, hAB, hC, bout);
        if (lv > 0) {
            int M = L * 32;
            dim3 g((M + 63) / 64, 7);    // N=800
            gemm2<1><<<g, 256, 0, stream>>>(obuf, Wout, Sout, nullptr,
                                            nullptr, hAB, hC, M, 800, DD, L, cb,
                                            DD + 1, 0, 400);
        }
    }
}

// Round 8
// 2573.850 us; speedup vs baseline: 1.6952x; 1.6207x over previous
//
#include <hip/hip_runtime.h>
#include <hip/hip_bf16.h>
#include <math.h>

// DIORA forward, MI355X. B=32, T=40, D_IN=1024, D=400.
// bf16-MFMA transform GEMMs (fp32 accumulate), fp32 score path.
// ws: hAB (32,820,800) bf16  [hA | hB]
//     hC  (32,820,400) fp32  (score transform; leaf pre-norm scratch early)
//     hH  (32,820,400) bf16  (bf16 copy of h: h_in during inside+prep, h_out after)
//     WinT (1200,400) bf16 K-major: [Win_top^T | Win_bot^T | Sin^T]
//     WoutT(1200,400) bf16 K-major: [Wout_top^T | Sout^T | Wout_bot^T]
// obuf (32,820,802) fp32 = d_out: [h_in 400 | s_in 1 | h_out 400 | s_out 1]

#define TLEN 40
#define DD 400
#define NCELL 820
#define STR 802

typedef short bf16x8 __attribute__((ext_vector_type(8)));
typedef float f32x4 __attribute__((ext_vector_type(4)));

__host__ __device__ __forceinline__ int coff(int l) { return l * TLEN - (l * (l - 1)) / 2; }
__device__ __forceinline__ float bf2f(unsigned short u) {
    return __uint_as_float(((unsigned)u) << 16);
}
__device__ __forceinline__ unsigned short f2bf(float v) {
    __hip_bfloat16 h = __float2bfloat16(v);
    return *reinterpret_cast<unsigned short*>(&h);
}

// ---------------- weight prep: bf16 K-major transposed copies ----------------
__global__ __launch_bounds__(256)
void prep_weights(const float* __restrict__ Win, const float* __restrict__ Sin,
                  const float* __restrict__ Wout, const float* __restrict__ Sout,
                  unsigned short* __restrict__ WinT, unsigned short* __restrict__ WoutT)
{
    int n = blockIdx.x;                 // 0..2399
    const float* src; int col; unsigned short* dst;
    if (n < 1200) {
        dst = WinT + (size_t)n * 400;
        if (n < 400)      { src = Win;             col = n; }
        else if (n < 800) { src = Win + 400 * 400; col = n - 400; }
        else              { src = Sin;             col = n - 800; }
    } else {
        int m = n - 1200;
        dst = WoutT + (size_t)m * 400;
        if (m < 400)      { src = Wout;             col = m; }
        else if (m < 800) { src = Sout;             col = m - 400; }
        else              { src = Wout + 400 * 400; col = m - 800; }
    }
    for (int k = threadIdx.x; k < 400; k += 256)
        dst[k] = f2bf(src[(size_t)k * 400 + col]);
}

// ---------------- bf16 MFMA GEMM: 64x128 tile, K=400 ----------------
// A = hH cell rows (bf16). Row r -> b=r/L, p=r%L, cell=cb+p.
// B = WT (bf16, K-major: WT[n][k]).
// col n < nsplit : Cb[cell*800 + co_b + n] (bf16); else Cf[cell*400 + n-nsplit] (fp32)
__global__ __launch_bounds__(256)
void mgemm(const unsigned short* __restrict__ A, const unsigned short* __restrict__ WT,
           unsigned short* __restrict__ Cb, float* __restrict__ Cf,
           int M, int N, int L, int cb, int co_b, int nsplit)
{
    __shared__ unsigned short As[64][40];
    __shared__ unsigned short Bs[128][40];
    const int tid = threadIdx.x;
    const int bm = blockIdx.x, bn = blockIdx.y;
    const int w = tid >> 6, lane = tid & 63;
    const int l15 = lane & 15, kb = (lane >> 4) * 8;

    // A stage: thread covers row ar, 8-elem chunk ach
    const int ar = tid >> 2, ach = (tid & 3) * 8;
    const int rg = bm * 64 + ar;
    const unsigned short* Ap = nullptr;
    if (rg < M) { int b = rg / L, p = rg - b * L;
                  Ap = A + ((size_t)(b * NCELL) + cb + p) * 400; }

    // B stage: thread covers col bcol, 16-elem half bh
    const int bcol = tid & 127, bh = (tid >> 7) * 16;
    const int ng = bn * 128 + bcol;
    const unsigned short* Bp = (ng < N) ? WT + (size_t)ng * 400 : nullptr;

    f32x4 acc[4][2];
    #pragma unroll
    for (int r = 0; r < 4; ++r)
        #pragma unroll
        for (int c = 0; c < 2; ++c) { f32x4 z = {0.f, 0.f, 0.f, 0.f}; acc[r][c] = z; }

    for (int k0 = 0; k0 < 400; k0 += 32) {
        int4 av = {0, 0, 0, 0};
        if (Ap && (k0 + ach) < 400) av = *(const int4*)(Ap + k0 + ach);
        int4 bv0 = {0, 0, 0, 0}, bv1 = {0, 0, 0, 0};
        if (Bp && (k0 + bh) < 400) {
            bv0 = *(const int4*)(Bp + k0 + bh);
            bv1 = *(const int4*)(Bp + k0 + bh + 8);
        }
        __syncthreads();
        *(int4*)&As[ar][ach] = av;
        *(int4*)&Bs[bcol][bh] = bv0;
        *(int4*)&Bs[bcol][bh + 8] = bv1;
        __syncthreads();

        bf16x8 af[4], bf[2];
        #pragma unroll
        for (int r = 0; r < 4; ++r) af[r] = *(const bf16x8*)&As[r * 16 + l15][kb];
        #pragma unroll
        for (int c = 0; c < 2; ++c) bf[c] = *(const bf16x8*)&Bs[w * 32 + c * 16 + l15][kb];
        #pragma unroll
        for (int r = 0; r < 4; ++r)
            #pragma unroll
            for (int c = 0; c < 2; ++c)
                acc[r][c] = __builtin_amdgcn_mfma_f32_16x16x32_bf16(af[r], bf[c], acc[r][c], 0, 0, 0);
    }

    const int rowb = (lane >> 4) * 4;
    #pragma unroll
    for (int r = 0; r < 4; ++r) {
        #pragma unroll
        for (int c = 0; c < 2; ++c) {
            int gcol = bn * 128 + w * 32 + c * 16 + l15;
            if (gcol >= N) continue;
            #pragma unroll
            for (int reg = 0; reg < 4; ++reg) {
                int rr = bm * 64 + r * 16 + rowb + reg;
                if (rr >= M) continue;
                int b = rr / L, p = rr - b * L;
                size_t cell = (size_t)(b * NCELL) + cb + p;
                float v = acc[r][c][reg];
                if (gcol < nsplit) Cb[cell * 800 + co_b + gcol] = f2bf(v);
                else               Cf[cell * 400 + (gcol - nsplit)] = v;
            }
        }
    }
}

// ---------------- leaf projection: fp32 VALU GEMM (1280x400x1024) ----------
__global__ __launch_bounds__(256)
void leaf_gemm(const float* __restrict__ A0, const float* __restrict__ B0,
               const float* __restrict__ bias, float* __restrict__ Cf)
{
    __shared__ float As[32][68];
    __shared__ float Bs[32][140];
    const int tid = threadIdx.x;
    const int bm = blockIdx.x, bn = blockIdx.y;
    const int M = 1280, N = 400, K = 1024;

    const int ar = tid & 63, ak = (tid >> 6) * 8;
    const int rg = bm * 64 + ar;
    const float* Ap = A0 + (size_t)rg * K;

    const int bk = tid >> 3, bc = (tid & 7) * 16;
    const int nb = bn * 128 + bc;
    const float* Bp = (nb < N) ? B0 + nb : nullptr;

    float acc[4][8];
    #pragma unroll
    for (int i = 0; i < 4; ++i)
        #pragma unroll
        for (int j = 0; j < 8; ++j) acc[i][j] = 0.f;

    const int ty = tid >> 4, tx = tid & 15;

    for (int k0 = 0; k0 < K; k0 += 32) {
        float4 p0 = *(const float4*)(Ap + k0 + ak);
        float4 p1 = *(const float4*)(Ap + k0 + ak + 4);
        float4 bv[4];
        if (Bp) {
            const float* bp = Bp + (size_t)(k0 + bk) * 400;
            bv[0] = *(const float4*)(bp);
            bv[1] = *(const float4*)(bp + 4);
            bv[2] = *(const float4*)(bp + 8);
            bv[3] = *(const float4*)(bp + 12);
        } else {
            bv[0] = bv[1] = bv[2] = bv[3] = make_float4(0.f, 0.f, 0.f, 0.f);
        }
        __syncthreads();
        As[ak + 0][ar] = p0.x; As[ak + 1][ar] = p0.y; As[ak + 2][ar] = p0.z; As[ak + 3][ar] = p0.w;
        As[ak + 4][ar] = p1.x; As[ak + 5][ar] = p1.y; As[ak + 6][ar] = p1.z; As[ak + 7][ar] = p1.w;
        *(float4*)&Bs[bk][bc + 0]  = bv[0];
        *(float4*)&Bs[bk][bc + 4]  = bv[1];
        *(float4*)&Bs[bk][bc + 8]  = bv[2];
        *(float4*)&Bs[bk][bc + 12] = bv[3];
        __syncthreads();

        #pragma unroll
        for (int k = 0; k < 32; ++k) {
            float4 a  = *(const float4*)&As[k][ty * 4];
            float4 b0 = *(const float4*)&Bs[k][tx * 4];
            float4 b1 = *(const float4*)&Bs[k][64 + tx * 4];
            float ai[4] = {a.x, a.y, a.z, a.w};
            float bj[8] = {b0.x, b0.y, b0.z, b0.w, b1.x, b1.y, b1.z, b1.w};
            #pragma unroll
            for (int i = 0; i < 4; ++i)
                #pragma unroll
                for (int j = 0; j < 8; ++j) acc[i][j] += ai[i] * bj[j];
        }
    }

    #pragma unroll
    for (int i = 0; i < 4; ++i) {
        int r = bm * 64 + ty * 4 + i;
        int b = r / TLEN, p = r - b * TLEN;
        size_t cell = (size_t)(b * NCELL) + p;
        #pragma unroll
        for (int j = 0; j < 8; ++j) {
            int n = bn * 128 + ((j < 4) ? (tx * 4 + j) : (64 + tx * 4 + j - 4));
            if (n >= N) continue;
            Cf[cell * 400 + n] = fmaxf(acc[i][j] + bias[n], 0.f);
        }
    }
}

// ---------------- normalize leaf rows (pre-norm scratch in hC) ----------
__global__ __launch_bounds__(256)
void unit_leaf(float* obuf, const float* __restrict__ hC, unsigned short* __restrict__ hH)
{
    int w = threadIdx.x >> 6, lane = threadIdx.x & 63;
    int r = blockIdx.x * 4 + w;                 // 0..1279 = (b, pos)
    int b = r / TLEN, pos = r - b * TLEN;
    const float* t = hC + ((size_t)b * NCELL + pos) * 400;
    float ss = 0.f;
    for (int f = lane; f < DD; f += 64) { float v = t[f]; ss += v * v; }
    #pragma unroll
    for (int o = 32; o; o >>= 1) ss += __shfl_xor(ss, o);
    float rinv = 1.f / (sqrtf(ss) + 1e-8f);
    size_t orow = ((size_t)b * NCELL + pos) * STR;
    size_t hrow = ((size_t)b * NCELL + pos) * 400;
    for (int f = lane; f < DD; f += 64) {
        float v = t[f] * rinv;
        obuf[orow + f] = v;
        hH[hrow + f] = f2bf(v);
    }
    if (lane == 0) obuf[orow + DD] = 0.f;       // s_in(leaf)=0
}

// ---------------- per-level compose ----------------
template<int INSIDE>
__global__ __launch_bounds__(256)
void compose_kernel(int lv, float* obuf, const unsigned short* __restrict__ hAB,
                    const float* __restrict__ hC, const float* __restrict__ bias,
                    unsigned short* __restrict__ hH)
{
    const int nk  = INSIDE ? lv : (TLEN - 1 - lv);
    const int b   = blockIdx.x & 31;
    const int pos = blockIdx.x >> 5;
    const int cell = coff(lv) + pos;
    const int tid = threadIdx.x;
    const int sA  = INSIDE ? DD : (STR - 1);  // s-term offset for i1 in obuf

    __shared__ int   o1s[TLEN], o2s[TLEN], c1s[TLEN], q1s[TLEN], q2s[TLEN];
    __shared__ float sbs[TLEN], ps[TLEN];
    __shared__ float bsh[DD];
    __shared__ float hnew[DD];
    __shared__ float red[4];
    __shared__ float sh_snew;

    if (tid < nk) {
        int k = tid, i1, i2;
        if (INSIDE) {
            i1 = coff(k) + pos;
            i2 = coff(lv - k - 1) + pos + k + 1;
        } else {
            if (k < pos) { i1 = coff(lv + k + 1) + pos - k - 1; i2 = coff(k) + pos - k - 1; }
            else         { int j = k - pos; i1 = coff(lv + j + 1) + pos; i2 = coff(j) + pos + lv + 1; }
        }
        o1s[k] = (b * NCELL + i1) * 800;        // hA (bf16)
        o2s[k] = (b * NCELL + i2) * 800 + 400;  // hB (bf16)
        c1s[k] = (b * NCELL + i1) * 400;        // hC (fp32, scores)
        q1s[k] = (b * NCELL + i1) * STR;
        q2s[k] = (b * NCELL + i2) * STR;
    }
    for (int f = tid; f < DD; f += 256) bsh[f] = bias[f];
    __syncthreads();

    // Phase A: scores sb_k = dot(hC[i1], h_in[i2]) + s1 + s2   (fp32, 16-lane groups)
    {
        const int g = tid >> 4, gl = tid & 15;
        for (int k = g; k < nk; k += 16) {
            const float2* v1 = (const float2*)(hC + c1s[k]);
            const float2* v2 = (const float2*)(obuf + q2s[k]);
            float ax = 0.f, ay = 0.f;
            for (int j = gl; j < 200; j += 16) {
                float2 a = v1[j], c = v2[j];
                ax += a.x * c.x; ay += a.y * c.y;
            }
            float acc = ax + ay;
            acc += __shfl_xor(acc, 8);
            acc += __shfl_xor(acc, 4);
            acc += __shfl_xor(acc, 2);
            acc += __shfl_xor(acc, 1);
            if (gl == 0)
                sbs[k] = acc + obuf[q1s[k] + sA] + obuf[q2s[k] + DD];
        }
    }
    __syncthreads();

    // softmax (wave 0), also s_new = sum p*sb
    if (tid < 64) {
        float v = (tid < nk) ? sbs[tid] : -INFINITY;
        float m = v;
        #pragma unroll
        for (int o = 32; o; o >>= 1) m = fmaxf(m, __shfl_xor(m, o));
        float e = (tid < nk) ? __expf(v - m) : 0.f;
        float s = e;
        #pragma unroll
        for (int o = 32; o; o >>= 1) s += __shfl_xor(s, o);
        float p = e / s;
        if (tid < nk) ps[tid] = p;
        float pv = (tid < nk) ? p * v : 0.f;
        #pragma unroll
        for (int o = 32; o; o >>= 1) pv += __shfl_xor(pv, o);
        if (tid == 0) sh_snew = pv;
    }
    __syncthreads();

    // Phase B: h_new = sum_k p_k * relu(hA[i1] + hB[i2] + bias)   (bf16 loads)
    if (tid < 200) {
        const int f = 2 * tid;
        const float bf0 = bsh[f], bf1 = bsh[f + 1];
        float ax = 0.f, ay = 0.f;
        #pragma unroll 4
        for (int k = 0; k < nk; ++k) {
            ushort2 a = *(const ushort2*)(hAB + o1s[k] + f);
            ushort2 c = *(const ushort2*)(hAB + o2s[k] + f);
            float p = ps[k];
            ax += p * fmaxf(bf2f(a.x) + bf2f(c.x) + bf0, 0.f);
            ay += p * fmaxf(bf2f(a.y) + bf2f(c.y) + bf1, 0.f);
        }
        hnew[f] = ax; hnew[f + 1] = ay;
    }
    __syncthreads();

    // norm
    float ss = 0.f;
    for (int f = tid; f < DD; f += 256) { float v = hnew[f]; ss += v * v; }
    #pragma unroll
    for (int o = 32; o; o >>= 1) ss += __shfl_xor(ss, o);
    if ((tid & 63) == 0) red[tid >> 6] = ss;
    __syncthreads();
    float rinv = 1.f / (sqrtf(red[0] + red[1] + red[2] + red[3]) + 1e-8f);

    const int hoff = INSIDE ? 0 : (DD + 1);
    const int soff = INSIDE ? DD : (STR - 1);
    size_t orow = ((size_t)(b * NCELL) + cell) * STR;
    size_t hrow = ((size_t)(b * NCELL) + cell) * 400;
    for (int f = tid; f < DD; f += 256) {
        float v = hnew[f] * rinv;
        obuf[orow + hoff + f] = v;
        hH[hrow + f] = f2bf(v);
    }
    if (tid == 0) obuf[orow + soff] = sh_snew;
}

// ---------------- root transforms: hA[root]=u@Wout_top (bf16), hC[root]=u@Sout
__global__ __launch_bounds__(256)
void root_trans(const float* __restrict__ rooth, const float* __restrict__ Wout,
                const float* __restrict__ Sout,
                unsigned short* __restrict__ hAB, float* __restrict__ hC)
{
    const int tid = threadIdx.x;
    __shared__ float u[DD];
    __shared__ float red[4];
    __shared__ float part[4][64];
    float ss = 0.f;
    for (int f = tid; f < DD; f += 256) { float v = rooth[f]; ss += v * v; }
    #pragma unroll
    for (int o = 32; o; o >>= 1) ss += __shfl_xor(ss, o);
    if ((tid & 63) == 0) red[tid >> 6] = ss;
    __syncthreads();
    float rinv = 1.f / (sqrtf(red[0] + red[1] + red[2] + red[3]) + 1e-8f);
    for (int f = tid; f < DD; f += 256) u[f] = rooth[f] * rinv;
    __syncthreads();

    const int w = tid >> 6, lane = tid & 63;
    const int n = blockIdx.x * 64 + lane;
    float acc = 0.f;
    if (n < 800) {
        int mat = n / DD;
        const float* Mp = mat ? Sout : Wout;
        int c = n - mat * DD;
        #pragma unroll 4
        for (int k = w * 100; k < w * 100 + 100; ++k) acc += u[k] * Mp[(size_t)k * DD + c];
    }
    part[w][lane] = acc;
    __syncthreads();
    if (w == 0 && n < 800) {
        float v = part[0][lane] + part[1][lane] + part[2][lane] + part[3][lane];
        if (n < 400) {
            unsigned short bv = f2bf(v);
            for (int b = 0; b < 32; ++b)
                hAB[((size_t)b * NCELL + NCELL - 1) * 800 + n] = bv;
        } else {
            for (int b = 0; b < 32; ++b)
                hC[((size_t)b * NCELL + NCELL - 1) * 400 + (n - 400)] = v;
        }
    }
}

// ---------------- root h_out/s_out into obuf ----------------
__global__ __launch_bounds__(256)
void root_write(const float* __restrict__ rooth, float* obuf)
{
    const int b = blockIdx.x;
    const int tid = threadIdx.x;
    __shared__ float red[4];
    float ss = 0.f;
    for (int f = tid; f < DD; f += 256) { float v = rooth[f]; ss += v * v; }
    #pragma unroll
    for (int o = 32; o; o >>= 1) ss += __shfl_xor(ss, o);
    if ((tid & 63) == 0) red[tid >> 6] = ss;
    __syncthreads();
    float rinv = 1.f / (sqrtf(red[0] + red[1] + red[2] + red[3]) + 1e-8f);
    size_t orow = ((size_t)b * NCELL + NCELL - 1) * STR;
    for (int f = tid; f < DD; f += 256) obuf[orow + DD + 1 + f] = rooth[f] * rinv;
    if (tid == 0) obuf[orow + STR - 1] = 0.f;
}

extern "C" void kernel_launch(void* const* d_in, const int* in_sizes, int n_in,
                              void* d_out, int out_size, void* d_ws, size_t ws_size,
                              hipStream_t stream)
{
    const float* x     = (const float*)d_in[0];
    const float* Wl    = (const float*)d_in[1];
    const float* blf   = (const float*)d_in[2];
    const float* Win   = (const float*)d_in[3];
    const float* bin   = (const float*)d_in[4];
    const float* Sin   = (const float*)d_in[5];
    const float* Wout  = (const float*)d_in[6];
    const float* bout  = (const float*)d_in[7];
    const float* Sout  = (const float*)d_in[8];
    const float* rooth = (const float*)d_in[9];

    float* obuf = (float*)d_out;
    unsigned short* hAB = (unsigned short*)d_ws;                    // 42 MB bf16
    float* hC = (float*)(hAB + (size_t)32 * NCELL * 800);           // 42 MB fp32
    unsigned short* hH = (unsigned short*)((char*)hC + (size_t)32 * NCELL * 400 * 4);  // 21 MB
    unsigned short* WinT  = hH + (size_t)32 * NCELL * 400;          // 0.96 MB
    unsigned short* WoutT = WinT + (size_t)1200 * 400;              // 0.96 MB

    prep_weights<<<2400, 256, 0, stream>>>(Win, Sin, Wout, Sout, WinT, WoutT);

    // leaf projection: relu(x @ W_leaf + b) -> hC scratch (fp32)
    leaf_gemm<<<dim3(20, 4), 256, 0, stream>>>(x, Wl, blf, hC);
    unit_leaf<<<320, 256, 0, stream>>>(obuf, hC, hH);

    // inside pass
    for (int lv = 0; lv < TLEN; ++lv) {
        int L = TLEN - lv;
        int cb = coff(lv);
        if (lv > 0)
            compose_kernel<1><<<L * 32, 256, 0, stream>>>(lv, obuf, hAB, hC, bin, hH);
        if (lv < TLEN - 1) {
            int M = L * 32;
            dim3 g((M + 63) / 64, 10);   // N=1200
            mgemm<<<g, 256, 0, stream>>>(hH, WinT, hAB, hC, M, 1200, L, cb, 0, 800);
        }
    }

    // prep: hAB[:, 400:800) = h_in @ W_out_bot for ALL cells (bf16)
    {
        dim3 g(410, 4);                  // M=26240/64, N=400/128
        mgemm<<<g, 256, 0, stream>>>(hH, WoutT + (size_t)800 * 400, hAB, hC,
                                     32 * NCELL, 400, NCELL, 0, 400, 400);
    }
    root_trans<<<13, 256, 0, stream>>>(rooth, Wout, Sout, hAB, hC);
    root_write<<<32, 256, 0, stream>>>(rooth, obuf);

    // outside pass
    for (int lv = TLEN - 2; lv >= 0; --lv) {
        int L = TLEN - lv;
        int cb = coff(lv);
        compose_kernel<0><<<L * 32, 256, 0, stream>>>(lv, obuf, hAB, hC, bout, hH);
        if (lv > 0) {
            int M = L * 32;
            dim3 g((M + 63) / 64, 7);    // N=800
            mgemm<<<g, 256, 0, stream>>>(hH, WoutT, hAB, hC, M, 800, L, cb, 0, 400);
        }
    }
}

// Round 9
// 2142.214 us; speedup vs baseline: 2.0368x; 1.2015x over previous
//
#include <hip/hip_runtime.h>
#include <hip/hip_bf16.h>
#include <math.h>

// DIORA forward, MI355X. B=32, T=40, D_IN=1024, D=400.
// All transform state bf16 (fp32 MFMA accumulate), fp32 s-path in obuf.
// ws layout (bf16 unless noted):
//   hAB  (32,820,800)  [hA | hB]
//   hCb  (32,820,400)  score transform (h@S)
//   hHin (32,820,400)  bf16 h_in  (written inside pass; read-only after)
//   hHout(32,820,400)  bf16 h_out (written outside pass; feeds outside mgemm)
//   WinT (1200,400) K-major [Win_top^T|Win_bot^T|Sin^T]
//   WoutT(1200,400) K-major [Wout_top^T|Sout^T|Wout_bot^T]
//   WlT  (400,1024) K-major W_leaf^T
//   leafS(1280,400) fp32 leaf pre-norm scratch
// obuf (32,820,802) fp32 = d_out: [h_in 400 | s_in 1 | h_out 400 | s_out 1]

#define TLEN 40
#define DD 400
#define NCELL 820
#define STR 802

typedef short bf16x8 __attribute__((ext_vector_type(8)));
typedef float f32x4 __attribute__((ext_vector_type(4)));

__host__ __device__ __forceinline__ int coff(int l) { return l * TLEN - (l * (l - 1)) / 2; }
__device__ __forceinline__ float bf2f(unsigned short u) {
    return __uint_as_float(((unsigned)u) << 16);
}
__device__ __forceinline__ unsigned short f2bf(float v) {
    __hip_bfloat16 h = __float2bfloat16(v);
    return *reinterpret_cast<unsigned short*>(&h);
}

// ---------------- weight prep: bf16 K-major transposed copies ----------------
__global__ __launch_bounds__(256)
void prep_weights(const float* __restrict__ Win, const float* __restrict__ Sin,
                  const float* __restrict__ Wout, const float* __restrict__ Sout,
                  const float* __restrict__ Wl,
                  unsigned short* __restrict__ WinT, unsigned short* __restrict__ WoutT,
                  unsigned short* __restrict__ WlT)
{
    int n = blockIdx.x;                 // 0..2799
    if (n < 2400) {
        const float* src; int col; unsigned short* dst;
        if (n < 1200) {
            dst = WinT + (size_t)n * 400;
            if (n < 400)      { src = Win;             col = n; }
            else if (n < 800) { src = Win + 400 * 400; col = n - 400; }
            else              { src = Sin;             col = n - 800; }
        } else {
            int m = n - 1200;
            dst = WoutT + (size_t)m * 400;
            if (m < 400)      { src = Wout;             col = m; }
            else if (m < 800) { src = Sout;             col = m - 400; }
            else              { src = Wout + 400 * 400; col = m - 800; }
        }
        for (int k = threadIdx.x; k < 400; k += 256)
            dst[k] = f2bf(src[(size_t)k * 400 + col]);
    } else {
        int m = n - 2400;               // 0..399
        unsigned short* dst = WlT + (size_t)m * 1024;
        for (int k = threadIdx.x; k < 1024; k += 256)
            dst[k] = f2bf(Wl[(size_t)k * 400 + m]);
    }
}

// ---------------- bf16 MFMA GEMM: 64x128 tile, K=400 ----------------
// A = bf16 cell rows. Row r -> b=r/L, p=r%L, cell=cb+p.
// B = WT (bf16, K-major). All outputs bf16:
//   col n < nsplit : Cb[cell*800 + co_b + n]; else Cc[cell*400 + n-nsplit]
__global__ __launch_bounds__(256)
void mgemm(const unsigned short* __restrict__ A, const unsigned short* __restrict__ WT,
           unsigned short* __restrict__ Cb, unsigned short* __restrict__ Cc,
           int M, int N, int L, int cb, int co_b, int nsplit)
{
    __shared__ unsigned short As[64][40];
    __shared__ unsigned short Bs[128][40];
    const int tid = threadIdx.x;
    const int bm = blockIdx.x, bn = blockIdx.y;
    const int w = tid >> 6, lane = tid & 63;
    const int l15 = lane & 15, kb = (lane >> 4) * 8;

    const int ar = tid >> 2, ach = (tid & 3) * 8;
    const int rg = bm * 64 + ar;
    const unsigned short* Ap = nullptr;
    if (rg < M) { int b = rg / L, p = rg - b * L;
                  Ap = A + ((size_t)(b * NCELL) + cb + p) * 400; }

    const int bcol = tid & 127, bh = (tid >> 7) * 16;
    const int ng = bn * 128 + bcol;
    const unsigned short* Bp = (ng < N) ? WT + (size_t)ng * 400 : nullptr;

    f32x4 acc[4][2];
    #pragma unroll
    for (int r = 0; r < 4; ++r)
        #pragma unroll
        for (int c = 0; c < 2; ++c) { f32x4 z = {0.f, 0.f, 0.f, 0.f}; acc[r][c] = z; }

    for (int k0 = 0; k0 < 400; k0 += 32) {
        int4 av = {0, 0, 0, 0};
        if (Ap && (k0 + ach) < 400) av = *(const int4*)(Ap + k0 + ach);
        int4 bv0 = {0, 0, 0, 0}, bv1 = {0, 0, 0, 0};
        if (Bp && (k0 + bh) < 400) {
            bv0 = *(const int4*)(Bp + k0 + bh);
            bv1 = *(const int4*)(Bp + k0 + bh + 8);
        }
        __syncthreads();
        *(int4*)&As[ar][ach] = av;
        *(int4*)&Bs[bcol][bh] = bv0;
        *(int4*)&Bs[bcol][bh + 8] = bv1;
        __syncthreads();

        bf16x8 af[4], bf[2];
        #pragma unroll
        for (int r = 0; r < 4; ++r) af[r] = *(const bf16x8*)&As[r * 16 + l15][kb];
        #pragma unroll
        for (int c = 0; c < 2; ++c) bf[c] = *(const bf16x8*)&Bs[w * 32 + c * 16 + l15][kb];
        #pragma unroll
        for (int r = 0; r < 4; ++r)
            #pragma unroll
            for (int c = 0; c < 2; ++c)
                acc[r][c] = __builtin_amdgcn_mfma_f32_16x16x32_bf16(af[r], bf[c], acc[r][c], 0, 0, 0);
    }

    const int rowb = (lane >> 4) * 4;
    #pragma unroll
    for (int r = 0; r < 4; ++r) {
        #pragma unroll
        for (int c = 0; c < 2; ++c) {
            int gcol = bn * 128 + w * 32 + c * 16 + l15;
            if (gcol >= N) continue;
            #pragma unroll
            for (int reg = 0; reg < 4; ++reg) {
                int rr = bm * 64 + r * 16 + rowb + reg;
                if (rr >= M) continue;
                int b = rr / L, p = rr - b * L;
                size_t cell = (size_t)(b * NCELL) + cb + p;
                unsigned short v = f2bf(acc[r][c][reg]);
                if (gcol < nsplit) Cb[cell * 800 + co_b + gcol] = v;
                else               Cc[cell * 400 + (gcol - nsplit)] = v;
            }
        }
    }
}

// ---------------- leaf MFMA GEMM: x(fp32,K=1024) @ WlT -> leafS fp32 ---------
__global__ __launch_bounds__(256)
void mleaf(const float* __restrict__ x, const unsigned short* __restrict__ WlT,
           const float* __restrict__ bias, float* __restrict__ leafS)
{
    __shared__ unsigned short As[64][40];
    __shared__ unsigned short Bs[128][40];
    const int tid = threadIdx.x;
    const int bm = blockIdx.x, bn = blockIdx.y;
    const int w = tid >> 6, lane = tid & 63;
    const int l15 = lane & 15, kb = (lane >> 4) * 8;

    const int ar = tid >> 2, ach = (tid & 3) * 8;
    const float* Ap = x + (size_t)(bm * 64 + ar) * 1024;

    const int bcol = tid & 127, bh = (tid >> 7) * 16;
    const int ng = bn * 128 + bcol;
    const unsigned short* Bp = (ng < 400) ? WlT + (size_t)ng * 1024 : nullptr;

    f32x4 acc[4][2];
    #pragma unroll
    for (int r = 0; r < 4; ++r)
        #pragma unroll
        for (int c = 0; c < 2; ++c) { f32x4 z = {0.f, 0.f, 0.f, 0.f}; acc[r][c] = z; }

    for (int k0 = 0; k0 < 1024; k0 += 32) {
        float4 p0 = *(const float4*)(Ap + k0 + ach);
        float4 p1 = *(const float4*)(Ap + k0 + ach + 4);
        unsigned short av[8];
        av[0] = f2bf(p0.x); av[1] = f2bf(p0.y); av[2] = f2bf(p0.z); av[3] = f2bf(p0.w);
        av[4] = f2bf(p1.x); av[5] = f2bf(p1.y); av[6] = f2bf(p1.z); av[7] = f2bf(p1.w);
        int4 bv0 = {0, 0, 0, 0}, bv1 = {0, 0, 0, 0};
        if (Bp) {
            bv0 = *(const int4*)(Bp + k0 + bh);
            bv1 = *(const int4*)(Bp + k0 + bh + 8);
        }
        __syncthreads();
        *(int4*)&As[ar][ach] = *(const int4*)av;
        *(int4*)&Bs[bcol][bh] = bv0;
        *(int4*)&Bs[bcol][bh + 8] = bv1;
        __syncthreads();

        bf16x8 af[4], bf[2];
        #pragma unroll
        for (int r = 0; r < 4; ++r) af[r] = *(const bf16x8*)&As[r * 16 + l15][kb];
        #pragma unroll
        for (int c = 0; c < 2; ++c) bf[c] = *(const bf16x8*)&Bs[w * 32 + c * 16 + l15][kb];
        #pragma unroll
        for (int r = 0; r < 4; ++r)
            #pragma unroll
            for (int c = 0; c < 2; ++c)
                acc[r][c] = __builtin_amdgcn_mfma_f32_16x16x32_bf16(af[r], bf[c], acc[r][c], 0, 0, 0);
    }

    const int rowb = (lane >> 4) * 4;
    #pragma unroll
    for (int r = 0; r < 4; ++r) {
        #pragma unroll
        for (int c = 0; c < 2; ++c) {
            int gcol = bn * 128 + w * 32 + c * 16 + l15;
            if (gcol >= 400) continue;
            float bv = bias[gcol];
            #pragma unroll
            for (int reg = 0; reg < 4; ++reg) {
                int rr = bm * 64 + r * 16 + rowb + reg;
                leafS[(size_t)rr * 400 + gcol] = fmaxf(acc[r][c][reg] + bv, 0.f);
            }
        }
    }
}

// ---------------- normalize leaf rows ----------
__global__ __launch_bounds__(256)
void unit_leaf(float* obuf, const float* __restrict__ leafS, unsigned short* __restrict__ hHin)
{
    int w = threadIdx.x >> 6, lane = threadIdx.x & 63;
    int r = blockIdx.x * 4 + w;                 // 0..1279 = (b, pos)
    int b = r / TLEN, pos = r - b * TLEN;
    const float* t = leafS + (size_t)r * 400;
    float ss = 0.f;
    for (int f = lane; f < DD; f += 64) { float v = t[f]; ss += v * v; }
    #pragma unroll
    for (int o = 32; o; o >>= 1) ss += __shfl_xor(ss, o);
    float rinv = 1.f / (sqrtf(ss) + 1e-8f);
    size_t orow = ((size_t)b * NCELL + pos) * STR;
    size_t hrow = ((size_t)b * NCELL + pos) * 400;
    for (int f = lane; f < DD; f += 64) {
        float v = t[f] * rinv;
        obuf[orow + f] = v;
        hHin[hrow + f] = f2bf(v);
    }
    if (lane == 0) obuf[orow + DD] = 0.f;       // s_in(leaf)=0
}

// ---------------- per-level compose ----------------
// Score path: hCb (bf16) . hHin (bf16) + fp32 s-terms from obuf.
// MLP path: hAB bf16. Output: obuf fp32 + hHw bf16.
template<int INSIDE>
__global__ __launch_bounds__(256)
void compose_kernel(int lv, float* obuf, const unsigned short* __restrict__ hAB,
                    const unsigned short* __restrict__ hCb,
                    const unsigned short* __restrict__ hHin,
                    unsigned short* __restrict__ hHw,
                    const float* __restrict__ bias)
{
    const int nk  = INSIDE ? lv : (TLEN - 1 - lv);
    const int b   = blockIdx.x & 31;
    const int pos = blockIdx.x >> 5;
    const int cell = coff(lv) + pos;
    const int tid = threadIdx.x;
    const int sA  = INSIDE ? DD : (STR - 1);  // s-term offset for i1 in obuf

    __shared__ int   o1s[TLEN], o2s[TLEN], c1s[TLEN], h2s[TLEN], q1s[TLEN], q2s[TLEN];
    __shared__ float sbs[TLEN], ps[TLEN];
    __shared__ float bsh[DD];
    __shared__ float hnew[DD];
    __shared__ float red[4];
    __shared__ float sh_snew;

    if (tid < nk) {
        int k = tid, i1, i2;
        if (INSIDE) {
            i1 = coff(k) + pos;
            i2 = coff(lv - k - 1) + pos + k + 1;
        } else {
            if (k < pos) { i1 = coff(lv + k + 1) + pos - k - 1; i2 = coff(k) + pos - k - 1; }
            else         { int j = k - pos; i1 = coff(lv + j + 1) + pos; i2 = coff(j) + pos + lv + 1; }
        }
        o1s[k] = (b * NCELL + i1) * 800;        // hA
        o2s[k] = (b * NCELL + i2) * 800 + 400;  // hB
        c1s[k] = (b * NCELL + i1) * 400;        // hCb (score)
        h2s[k] = (b * NCELL + i2) * 400;        // hHin (score)
        q1s[k] = (b * NCELL + i1) * STR;
        q2s[k] = (b * NCELL + i2) * STR;
    }
    for (int f = tid; f < DD; f += 256) bsh[f] = bias[f];
    __syncthreads();

    // Phase A: scores sb_k = dot(hCb[i1], hHin[i2]) + s1 + s2
    {
        const int g = tid >> 4, gl = tid & 15;
        for (int k = g; k < nk; k += 16) {
            const unsigned short* v1 = hCb + c1s[k];
            const unsigned short* v2 = hHin + h2s[k];
            float acc = 0.f;
            for (int j = gl * 4; j < 400; j += 64) {
                ushort4 a = *(const ushort4*)(v1 + j);
                ushort4 c = *(const ushort4*)(v2 + j);
                acc += bf2f(a.x) * bf2f(c.x) + bf2f(a.y) * bf2f(c.y)
                     + bf2f(a.z) * bf2f(c.z) + bf2f(a.w) * bf2f(c.w);
            }
            acc += __shfl_xor(acc, 8);
            acc += __shfl_xor(acc, 4);
            acc += __shfl_xor(acc, 2);
            acc += __shfl_xor(acc, 1);
            if (gl == 0)
                sbs[k] = acc + obuf[q1s[k] + sA] + obuf[q2s[k] + DD];
        }
    }
    __syncthreads();

    // softmax (wave 0), also s_new = sum p*sb
    if (tid < 64) {
        float v = (tid < nk) ? sbs[tid] : -INFINITY;
        float m = v;
        #pragma unroll
        for (int o = 32; o; o >>= 1) m = fmaxf(m, __shfl_xor(m, o));
        float e = (tid < nk) ? __expf(v - m) : 0.f;
        float s = e;
        #pragma unroll
        for (int o = 32; o; o >>= 1) s += __shfl_xor(s, o);
        float p = e / s;
        if (tid < nk) ps[tid] = p;
        float pv = (tid < nk) ? p * v : 0.f;
        #pragma unroll
        for (int o = 32; o; o >>= 1) pv += __shfl_xor(pv, o);
        if (tid == 0) sh_snew = pv;
    }
    __syncthreads();

    // Phase B: h_new = sum_k p_k * relu(hA[i1] + hB[i2] + bias)
    if (tid < 200) {
        const int f = 2 * tid;
        const float bf0 = bsh[f], bf1 = bsh[f + 1];
        float ax = 0.f, ay = 0.f;
        #pragma unroll 4
        for (int k = 0; k < nk; ++k) {
            ushort2 a = *(const ushort2*)(hAB + o1s[k] + f);
            ushort2 c = *(const ushort2*)(hAB + o2s[k] + f);
            float p = ps[k];
            ax += p * fmaxf(bf2f(a.x) + bf2f(c.x) + bf0, 0.f);
            ay += p * fmaxf(bf2f(a.y) + bf2f(c.y) + bf1, 0.f);
        }
        hnew[f] = ax; hnew[f + 1] = ay;
    }
    __syncthreads();

    // norm
    float ss = 0.f;
    for (int f = tid; f < DD; f += 256) { float v = hnew[f]; ss += v * v; }
    #pragma unroll
    for (int o = 32; o; o >>= 1) ss += __shfl_xor(ss, o);
    if ((tid & 63) == 0) red[tid >> 6] = ss;
    __syncthreads();
    float rinv = 1.f / (sqrtf(red[0] + red[1] + red[2] + red[3]) + 1e-8f);

    const int hoff = INSIDE ? 0 : (DD + 1);
    const int soff = INSIDE ? DD : (STR - 1);
    size_t orow = ((size_t)(b * NCELL) + cell) * STR;
    size_t hrow = ((size_t)(b * NCELL) + cell) * 400;
    for (int f = tid; f < DD; f += 256) {
        float v = hnew[f] * rinv;
        obuf[orow + hoff + f] = v;
        hHw[hrow + f] = f2bf(v);
    }
    if (tid == 0) obuf[orow + soff] = sh_snew;
}

// ---------------- root transforms: hAB[root][0:400)=u@Wout_top, hCb[root]=u@Sout
__global__ __launch_bounds__(256)
void root_trans(const float* __restrict__ rooth, const float* __restrict__ Wout,
                const float* __restrict__ Sout,
                unsigned short* __restrict__ hAB, unsigned short* __restrict__ hCb)
{
    const int tid = threadIdx.x;
    __shared__ float u[DD];
    __shared__ float red[4];
    __shared__ float part[4][64];
    float ss = 0.f;
    for (int f = tid; f < DD; f += 256) { float v = rooth[f]; ss += v * v; }
    #pragma unroll
    for (int o = 32; o; o >>= 1) ss += __shfl_xor(ss, o);
    if ((tid & 63) == 0) red[tid >> 6] = ss;
    __syncthreads();
    float rinv = 1.f / (sqrtf(red[0] + red[1] + red[2] + red[3]) + 1e-8f);
    for (int f = tid; f < DD; f += 256) u[f] = rooth[f] * rinv;
    __syncthreads();

    const int w = tid >> 6, lane = tid & 63;
    const int n = blockIdx.x * 64 + lane;
    float acc = 0.f;
    if (n < 800) {
        int mat = n / DD;
        const float* Mp = mat ? Sout : Wout;
        int c = n - mat * DD;
        #pragma unroll 4
        for (int k = w * 100; k < w * 100 + 100; ++k) acc += u[k] * Mp[(size_t)k * DD + c];
    }
    part[w][lane] = acc;
    __syncthreads();
    if (w == 0 && n < 800) {
        float v = part[0][lane] + part[1][lane] + part[2][lane] + part[3][lane];
        unsigned short bv = f2bf(v);
        if (n < 400) {
            for (int b = 0; b < 32; ++b)
                hAB[((size_t)b * NCELL + NCELL - 1) * 800 + n] = bv;
        } else {
            for (int b = 0; b < 32; ++b)
                hCb[((size_t)b * NCELL + NCELL - 1) * 400 + (n - 400)] = bv;
        }
    }
}

// ---------------- root h_out/s_out into obuf ----------------
__global__ __launch_bounds__(256)
void root_write(const float* __restrict__ rooth, float* obuf)
{
    const int b = blockIdx.x;
    const int tid = threadIdx.x;
    __shared__ float red[4];
    float ss = 0.f;
    for (int f = tid; f < DD; f += 256) { float v = rooth[f]; ss += v * v; }
    #pragma unroll
    for (int o = 32; o; o >>= 1) ss += __shfl_xor(ss, o);
    if ((tid & 63) == 0) red[tid >> 6] = ss;
    __syncthreads();
    float rinv = 1.f / (sqrtf(red[0] + red[1] + red[2] + red[3]) + 1e-8f);
    size_t orow = ((size_t)b * NCELL + NCELL - 1) * STR;
    for (int f = tid; f < DD; f += 256) obuf[orow + DD + 1 + f] = rooth[f] * rinv;
    if (tid == 0) obuf[orow + STR - 1] = 0.f;
}

extern "C" void kernel_launch(void* const* d_in, const int* in_sizes, int n_in,
                              void* d_out, int out_size, void* d_ws, size_t ws_size,
                              hipStream_t stream)
{
    const float* x     = (const float*)d_in[0];
    const float* Wl    = (const float*)d_in[1];
    const float* blf   = (const float*)d_in[2];
    const float* Win   = (const float*)d_in[3];
    const float* bin   = (const float*)d_in[4];
    const float* Sin   = (const float*)d_in[5];
    const float* Wout  = (const float*)d_in[6];
    const float* bout  = (const float*)d_in[7];
    const float* Sout  = (const float*)d_in[8];
    const float* rooth = (const float*)d_in[9];

    float* obuf = (float*)d_out;
    unsigned short* hAB   = (unsigned short*)d_ws;          // 42 MB
    unsigned short* hCb   = hAB   + (size_t)32 * NCELL * 800;   // 21 MB
    unsigned short* hHin  = hCb   + (size_t)32 * NCELL * 400;   // 21 MB
    unsigned short* hHout = hHin  + (size_t)32 * NCELL * 400;   // 21 MB
    unsigned short* WinT  = hHout + (size_t)32 * NCELL * 400;   // 0.96 MB
    unsigned short* WoutT = WinT  + (size_t)1200 * 400;         // 0.96 MB
    unsigned short* WlT   = WoutT + (size_t)1200 * 400;         // 0.82 MB
    float* leafS = (float*)(WlT + (size_t)400 * 1024);          // 2 MB fp32

    prep_weights<<<2800, 256, 0, stream>>>(Win, Sin, Wout, Sout, Wl, WinT, WoutT, WlT);

    // leaf projection (MFMA): relu(x @ W_leaf + b) -> leafS
    mleaf<<<dim3(20, 4), 256, 0, stream>>>(x, WlT, blf, leafS);
    unit_leaf<<<320, 256, 0, stream>>>(obuf, leafS, hHin);

    // inside pass
    for (int lv = 0; lv < TLEN; ++lv) {
        int L = TLEN - lv;
        int cb = coff(lv);
        if (lv > 0)
            compose_kernel<1><<<L * 32, 256, 0, stream>>>(lv, obuf, hAB, hCb, hHin, hHin, bin);
        if (lv < TLEN - 1) {
            int M = L * 32;
            dim3 g((M + 63) / 64, 10);   // N=1200
            mgemm<<<g, 256, 0, stream>>>(hHin, WinT, hAB, hCb, M, 1200, L, cb, 0, 800);
        }
    }

    // prep: hAB[:, 400:800) = h_in @ W_out_bot for ALL cells
    {
        dim3 g(410, 4);                  // M=26240/64, N=400/128
        mgemm<<<g, 256, 0, stream>>>(hHin, WoutT + (size_t)800 * 400, hAB, hCb,
                                     32 * NCELL, 400, NCELL, 0, 400, 400);
    }
    root_trans<<<13, 256, 0, stream>>>(rooth, Wout, Sout, hAB, hCb);
    root_write<<<32, 256, 0, stream>>>(rooth, obuf);

    // outside pass
    for (int lv = TLEN - 2; lv >= 0; --lv) {
        int L = TLEN - lv;
        int cb = coff(lv);
        compose_kernel<0><<<L * 32, 256, 0, stream>>>(lv, obuf, hAB, hCb, hHin, hHout, bout);
        if (lv > 0) {
            int M = L * 32;
            dim3 g((M + 63) / 64, 7);    // N=800
            mgemm<<<g, 256, 0, stream>>>(hHout, WoutT, hAB, hCb, M, 800, L, cb, 0, 400);
        }
    }
}